// Round 1
// baseline (101.822 us; speedup 1.0000x reference)
//
#include <hip/hip_runtime.h>

// RLS step: one 256-thread block per batch row b.
// Thread t owns 16 P elements: float4 #k at flat float4 index k*256+t
//   -> rows i = (t>>4) + 16k, cols 4*(t&15)..+3.
// Loads and stores of P are perfectly coalesced (contiguous 4KB per instr).

constexpr int T = 64;

__global__ __launch_bounds__(256) void rls_step(
    const float* __restrict__ x,       // (B,64)
    const float* __restrict__ d,       // (B,)
    const float* __restrict__ w_prev,  // (B,64)
    const float* __restrict__ P_prev,  // (B,64,64)
    const float* __restrict__ ffp,     // (1,)
    float* __restrict__ w_next,        // (B,64)
    float* __restrict__ P_next,        // (B,64,64)
    float* __restrict__ y_hat)         // (B,)
{
    const int b    = blockIdx.x;
    const int t    = threadIdx.x;   // 0..255
    const int lane = t & 63;

    __shared__ float x_s[T];
    __shared__ float w_s[T];
    __shared__ float Px_s[T];
    __shared__ float xP_part[16][T];  // per-group partial column sums
    __shared__ float xP_s[T];
    __shared__ float g_s[T];
    __shared__ float sc[2];           // sc[0]=inv_denom, sc[1]=error

    const float lam     = fminf(fmaxf(ffp[0], 1.0e-4f), 0.9999f);
    const float inv_lam = 1.0f / lam;

    const float4* __restrict__ Pv  =
        reinterpret_cast<const float4*>(P_prev) + (size_t)b * (T * T / 4);
    float4* __restrict__ Pnv =
        reinterpret_cast<float4*>(P_next) + (size_t)b * (T * T / 4);

    // Issue the P loads first so they're in flight during LDS staging.
    float4 p0 = Pv[0 * 256 + t];
    float4 p1 = Pv[1 * 256 + t];
    float4 p2 = Pv[2 * 256 + t];
    float4 p3 = Pv[3 * 256 + t];

    if (t < T)            x_s[t]     = x[(size_t)b * T + t];
    else if (t < 2 * T)   w_s[t - T] = w_prev[(size_t)b * T + (t - T)];
    __syncthreads();

    const int grp = t >> 4;          // 0..15 ; rows grp + 16k
    const int c0  = (t & 15) * 4;    // cols c0..c0+3

    const float xc0 = x_s[c0 + 0], xc1 = x_s[c0 + 1];
    const float xc2 = x_s[c0 + 2], xc3 = x_s[c0 + 3];

    // ---- Px[i] = sum_j P[i][j] x[j] : reduce over 16 lanes sharing grp ----
    {
        float part;
        // k = 0
        part = p0.x * xc0 + p0.y * xc1 + p0.z * xc2 + p0.w * xc3;
        part += __shfl_xor(part, 1); part += __shfl_xor(part, 2);
        part += __shfl_xor(part, 4); part += __shfl_xor(part, 8);
        if ((t & 15) == 0) Px_s[grp + 0]  = part;
        // k = 1
        part = p1.x * xc0 + p1.y * xc1 + p1.z * xc2 + p1.w * xc3;
        part += __shfl_xor(part, 1); part += __shfl_xor(part, 2);
        part += __shfl_xor(part, 4); part += __shfl_xor(part, 8);
        if ((t & 15) == 0) Px_s[grp + 16] = part;
        // k = 2
        part = p2.x * xc0 + p2.y * xc1 + p2.z * xc2 + p2.w * xc3;
        part += __shfl_xor(part, 1); part += __shfl_xor(part, 2);
        part += __shfl_xor(part, 4); part += __shfl_xor(part, 8);
        if ((t & 15) == 0) Px_s[grp + 32] = part;
        // k = 3
        part = p3.x * xc0 + p3.y * xc1 + p3.z * xc2 + p3.w * xc3;
        part += __shfl_xor(part, 1); part += __shfl_xor(part, 2);
        part += __shfl_xor(part, 4); part += __shfl_xor(part, 8);
        if ((t & 15) == 0) Px_s[grp + 48] = part;
    }

    // ---- xP[j] partials: sum over this thread's 4 rows ----
    {
        const float xi0 = x_s[grp +  0];
        const float xi1 = x_s[grp + 16];
        const float xi2 = x_s[grp + 32];
        const float xi3 = x_s[grp + 48];
        float s0 = xi0 * p0.x + xi1 * p1.x + xi2 * p2.x + xi3 * p3.x;
        float s1 = xi0 * p0.y + xi1 * p1.y + xi2 * p2.y + xi3 * p3.y;
        float s2 = xi0 * p0.z + xi1 * p1.z + xi2 * p2.z + xi3 * p3.z;
        float s3 = xi0 * p0.w + xi1 * p1.w + xi2 * p2.w + xi3 * p3.w;
        *reinterpret_cast<float4*>(&xP_part[grp][c0]) = make_float4(s0, s1, s2, s3);
    }
    __syncthreads();

    if (t < 64) {
        // finish xP: sum the 16 group partials (column-consecutive -> no bank conflicts)
        float s = 0.0f;
        #pragma unroll
        for (int gg = 0; gg < 16; ++gg) s += xP_part[gg][t];
        xP_s[t] = s;
    } else if (t < 128) {
        // denom = lam + x . Px
        float v = x_s[lane] * Px_s[lane];
        v += __shfl_xor(v, 1);  v += __shfl_xor(v, 2);  v += __shfl_xor(v, 4);
        v += __shfl_xor(v, 8);  v += __shfl_xor(v, 16); v += __shfl_xor(v, 32);
        if (lane == 0) sc[0] = 1.0f / (lam + v);
    } else if (t < 192) {
        // y_hat = w . x ; error = d - y_hat
        float v = w_s[lane] * x_s[lane];
        v += __shfl_xor(v, 1);  v += __shfl_xor(v, 2);  v += __shfl_xor(v, 4);
        v += __shfl_xor(v, 8);  v += __shfl_xor(v, 16); v += __shfl_xor(v, 32);
        if (lane == 0) {
            y_hat[b] = v;
            sc[1]    = d[b] - v;
        }
    }
    __syncthreads();

    if (t < 64) {
        const float gj = Px_s[t] * sc[0];
        g_s[t] = gj;
        w_next[(size_t)b * T + t] = w_s[t] + gj * sc[1];
    }
    __syncthreads();

    // ---- P_next = (P - g (x^T P)) / lam, from still-live registers ----
    {
        const float xq0 = xP_s[c0 + 0], xq1 = xP_s[c0 + 1];
        const float xq2 = xP_s[c0 + 2], xq3 = xP_s[c0 + 3];
        const float g0 = g_s[grp +  0];
        const float g1 = g_s[grp + 16];
        const float g2 = g_s[grp + 32];
        const float g3 = g_s[grp + 48];
        float4 o;
        o.x = (p0.x - g0 * xq0) * inv_lam;
        o.y = (p0.y - g0 * xq1) * inv_lam;
        o.z = (p0.z - g0 * xq2) * inv_lam;
        o.w = (p0.w - g0 * xq3) * inv_lam;
        Pnv[0 * 256 + t] = o;
        o.x = (p1.x - g1 * xq0) * inv_lam;
        o.y = (p1.y - g1 * xq1) * inv_lam;
        o.z = (p1.z - g1 * xq2) * inv_lam;
        o.w = (p1.w - g1 * xq3) * inv_lam;
        Pnv[1 * 256 + t] = o;
        o.x = (p2.x - g2 * xq0) * inv_lam;
        o.y = (p2.y - g2 * xq1) * inv_lam;
        o.z = (p2.z - g2 * xq2) * inv_lam;
        o.w = (p2.w - g2 * xq3) * inv_lam;
        Pnv[2 * 256 + t] = o;
        o.x = (p3.x - g3 * xq0) * inv_lam;
        o.y = (p3.y - g3 * xq1) * inv_lam;
        o.z = (p3.z - g3 * xq2) * inv_lam;
        o.w = (p3.w - g3 * xq3) * inv_lam;
        Pnv[3 * 256 + t] = o;
    }
}

extern "C" void kernel_launch(void* const* d_in, const int* in_sizes, int n_in,
                              void* d_out, int out_size, void* d_ws, size_t ws_size,
                              hipStream_t stream) {
    const float* x      = (const float*)d_in[0];
    const float* d      = (const float*)d_in[1];
    const float* w_prev = (const float*)d_in[2];
    const float* P_prev = (const float*)d_in[3];
    const float* ffp    = (const float*)d_in[4];

    const int B = in_sizes[1];   // d has B elements

    float* out    = (float*)d_out;
    float* w_next = out;
    float* P_next = out + (size_t)B * T;
    float* y_hat  = out + (size_t)B * T + (size_t)B * T * T;

    rls_step<<<B, 256, 0, stream>>>(x, d, w_prev, P_prev, ffp,
                                    w_next, P_next, y_hat);
}